// Round 5
// baseline (169.168 us; speedup 1.0000x reference)
//
#include <hip/hip_runtime.h>

typedef __bf16 bf16x8 __attribute__((ext_vector_type(8)));
typedef float f32x4 __attribute__((ext_vector_type(4)));

// ---------------------------------------------------------------------------
// Workspace layout (bytes):
#define OFF_BSF   0x000000   // f32  [4][256][1024]  4 MB
#define OFF_BSFT  0x400000   // bf16 [4][1024][256]  2 MB   (spatial-major)
#define OFF_BSFB  0x600000   // bf16 [4][256][1024]  2 MB   (ch-major; reused as Yt in P1+)
#define OFF_YT    0x600000   // bf16 [4][1024][256]  2 MB   Yt[j][c] = (V.bsf)^T
#define OFF_Z     0x800000   // f32  [4][256][1024]  4 MB
#define OFF_SBH   0xC00000   // bf16 [4][256][256]   512 KB  S hi
#define OFF_SBL   0xC80000   // bf16 [4][256][256]   512 KB  S lo (residual)
#define OFF_T0    0xD00000   // bf16 [4][256][256]   T0' = U*S + uv*r^T
#define OFF_OWB   0xE00000   // bf16 [256][256]
#define OFF_GWT   0xE20000   // bf16 g_w^T
#define OFF_PHT   0xE40000   // bf16 ph_w^T
#define OFF_THT   0xE60000   // bf16 th_w^T
#define OFF_UB    0xE80000   // bf16 U = ow*g_w
#define OFF_VB    0xEA0000   // bf16 V = ph_w^T*th_w
#define OFF_RPART 0xEE0000   // f32 [16][1024] row-sum partials
#define OFF_R     0xEF0000   // f32 [4][256]  r = bsf.1
#define OFF_UV    0xEF1000   // f32 [256]  u = ow*g_b
#define OFF_V2    0xEF1400   // f32 [256]  v2 = ph_w^T*th_b
#define OFF_W2    0xEF1800   // f32 [256]  w2 = th_w^T*ph_b
#define OFF_S2    0xEF1C00   // f32 s2 = ph_b.th_b
#define OFF_CVEC  0xEF2000   // f32 [4][256]  U*r
#define OFF_QV    0xEF4000   // f32 [4][256]  per-channel constant of z
#define OFF_STATS 0xEF9000   // f32 [4][32][2] RAW (sum, sumsq) via atomics
#define OFF_W2SP  0xEFA000   // f32 [4][1024] w2sp = w2^T . bsf
// ---------------------------------------------------------------------------

// ---------------- prep: gather + weight cvt/transpose + bias matvecs --------
__global__ __launch_bounds__(256) void prep_k(
    const float* __restrict__ f0, const float* __restrict__ f1,
    const float* __restrict__ f2, const float* __restrict__ f3,
    const float* __restrict__ f4,
    const float* __restrict__ g_w, const float* __restrict__ ph_w,
    const float* __restrict__ th_w, const float* __restrict__ ow_w,
    const float* __restrict__ g_b, const float* __restrict__ ph_b,
    const float* __restrict__ th_b,
    char* __restrict__ ws)
{
  const int blk = blockIdx.x, t = threadIdx.x;
  __shared__ __attribute__((aligned(16))) union {
    __bf16 Lt[64][66];
    __bf16 T[64][72];
    float vec[256];
  } sm;

  if (blk < 256) {
    // ---- gather: bsf fp32 + bsfB bf16 (ch-major) + bsfT bf16 (sp-major) + rowsum partials
    float*  bsf   = (float*)(ws + OFF_BSF);
    __bf16* bsfT  = (__bf16*)(ws + OFF_BSFT);
    __bf16* bsfB  = (__bf16*)(ws + OFF_BSFB);
    float*  rpart = (float*)(ws + OFF_RPART);
    const int sblk = blk & 15, cblk = (blk >> 4) & 3, b = blk >> 6;
    const int c0 = cblk * 64, s0 = sblk * 64;
    const int spl = t & 63, sp = s0 + spl;
    const int y = sp >> 5, x = sp & 31;
#pragma unroll
    for (int i = 0; i < 16; ++i) {
      const int cl = (t >> 6) + i * 4;
      const int nc = b * 256 + c0 + cl;

      const float* p0 = f0 + (size_t)nc * 16384 + (y * 4) * 128 + x * 4;
      float4 r0 = *(const float4*)(p0);
      float4 r1 = *(const float4*)(p0 + 128);
      float4 r2 = *(const float4*)(p0 + 256);
      float4 r3 = *(const float4*)(p0 + 384);
      float a  = fmaxf(fmaxf(r0.x, r0.y), fmaxf(r0.z, r0.w));
      float bb = fmaxf(fmaxf(r1.x, r1.y), fmaxf(r1.z, r1.w));
      float c  = fmaxf(fmaxf(r2.x, r2.y), fmaxf(r2.z, r2.w));
      float d  = fmaxf(fmaxf(r3.x, r3.y), fmaxf(r3.z, r3.w));
      float m0v = fmaxf(fmaxf(a, bb), fmaxf(c, d));

      const float* p1 = f1 + (size_t)nc * 4096 + (y * 2) * 64 + x * 2;
      float2 s0v = *(const float2*)(p1);
      float2 s1v = *(const float2*)(p1 + 64);
      float m1v = fmaxf(fmaxf(s0v.x, s0v.y), fmaxf(s1v.x, s1v.y));

      float v2 = f2[(size_t)nc * 1024 + sp];
      float v3 = f3[(size_t)nc * 256 + (y >> 1) * 16 + (x >> 1)];
      float v4 = f4[(size_t)nc * 64  + (y >> 2) * 8  + (x >> 2)];
      float val = (m0v + m1v + v2 + v3 + v4) * 0.2f;
      bsf[(size_t)nc * 1024 + sp]  = val;
      bsfB[(size_t)nc * 1024 + sp] = (__bf16)val;
      sm.Lt[cl][spl] = (__bf16)val;
      float rs = val;
#pragma unroll
      for (int off = 32; off; off >>= 1) rs += __shfl_down(rs, off);
      if (spl == 0) rpart[sblk * 1024 + nc] = rs;
    }
    __syncthreads();
#pragma unroll
    for (int i = 0; i < 16; ++i) {
      int linear = t + i * 256;
      int spl2 = linear >> 6, cl2 = linear & 63;
      bsfT[((size_t)b * 1024 + s0 + spl2) * 256 + c0 + cl2] = sm.Lt[cl2][spl2];
    }
  } else if (blk < 304) {
    // ---- weight transposes (fp32 -> bf16): gwT/phT/thT, 64x64 tiles
    const int w = (blk - 256) >> 4, tl = (blk - 256) & 15;
    const float* src = (w == 0) ? g_w : (w == 1) ? ph_w : th_w;
    __bf16* dst = (__bf16*)(ws + ((w == 0) ? OFF_GWT : (w == 1) ? OFF_PHT : OFF_THT));
    const int ti = (tl >> 2) * 64, tj = (tl & 3) * 64;
#pragma unroll
    for (int i = 0; i < 4; ++i) {
      int idx = i * 256 + t;
      int r = idx >> 4, c4 = (idx & 15) << 2;
      float4 v = *(const float4*)&src[(size_t)(ti + r) * 256 + tj + c4];
      sm.T[c4 + 0][r] = (__bf16)v.x;
      sm.T[c4 + 1][r] = (__bf16)v.y;
      sm.T[c4 + 2][r] = (__bf16)v.z;
      sm.T[c4 + 3][r] = (__bf16)v.w;
    }
    __syncthreads();
#pragma unroll
    for (int i = 0; i < 2; ++i) {
      int idx = i * 256 + t;
      int aa = idx >> 3, cc = (idx & 7) << 3;
      bf16x8 o = *(const bf16x8*)&sm.T[aa][cc];
      *(bf16x8*)&dst[(size_t)(tj + aa) * 256 + ti + cc] = o;
    }
  } else if (blk < 308) {
    // ---- owB plain convert
    const int r0 = (blk - 304) * 64;
    __bf16* owB = (__bf16*)(ws + OFF_OWB);
#pragma unroll
    for (int i = 0; i < 8; ++i) {
      int lin = i * 2048 + t * 8;
      size_t gidx = (size_t)r0 * 256 + lin;
      float4 v0 = *(const float4*)&ow_w[gidx];
      float4 v1 = *(const float4*)&ow_w[gidx + 4];
      bf16x8 o;
      o[0] = (__bf16)v0.x; o[1] = (__bf16)v0.y; o[2] = (__bf16)v0.z; o[3] = (__bf16)v0.w;
      o[4] = (__bf16)v1.x; o[5] = (__bf16)v1.y; o[6] = (__bf16)v1.z; o[7] = (__bf16)v1.w;
      *(bf16x8*)&owB[gidx] = o;
    }
  } else if (blk == 308) {
    // ---- u = ow_w . g_b ; zero raw GN stats
    float* uv = (float*)(ws + OFF_UV);
    sm.vec[t] = g_b[t];
    __syncthreads();
    const int wv = t >> 6, l = t & 63;
    for (int rr = 0; rr < 64; ++rr) {
      int row = wv * 64 + rr;
      const float* p = ow_w + (size_t)row * 256;
      float pa = p[l] * sm.vec[l] + p[64 + l] * sm.vec[64 + l]
               + p[128 + l] * sm.vec[128 + l] + p[192 + l] * sm.vec[192 + l];
#pragma unroll
      for (int off = 32; off; off >>= 1) pa += __shfl_down(pa, off);
      if (l == 0) uv[row] = pa;
    }
    ((float*)(ws + OFF_STATS))[t] = 0.f;
  } else if (blk == 309) {
    // ---- v2 = ph_w^T . th_b (column dot, coalesced) ; s2 = ph_b.th_b
    float* v2 = (float*)(ws + OFF_V2);
    float* s2 = (float*)(ws + OFF_S2);
    float acc = 0.f;
#pragma unroll 8
    for (int c = 0; c < 256; ++c) acc += ph_w[(size_t)c * 256 + t] * th_b[c];
    v2[t] = acc;
    if (t < 64) {
      float pa = ph_b[t] * th_b[t] + ph_b[64 + t] * th_b[64 + t]
               + ph_b[128 + t] * th_b[128 + t] + ph_b[192 + t] * th_b[192 + t];
#pragma unroll
      for (int off = 32; off; off >>= 1) pa += __shfl_down(pa, off);
      if (t == 0) s2[0] = pa;
    }
  } else {
    // ---- w2 = th_w^T . ph_b
    float* w2 = (float*)(ws + OFF_W2);
    float acc = 0.f;
#pragma unroll 8
    for (int c = 0; c < 256; ++c) acc += th_w[(size_t)c * 256 + t] * ph_b[c];
    w2[t] = acc;
  }
}

// ---------------- GEMM accumulate core (64x64 tile, 4 waves, dbuf) ----------
__device__ __forceinline__ void gemm_acc(
    const __bf16* __restrict__ A, const __bf16* __restrict__ B,
    const int K, const int m0, const int n0,
    __bf16 (*Al)[64][72], __bf16 (*Bl)[64][72],
    f32x4 acc[2][2])
{
  const int t = threadIdx.x;
  const int lane = t & 63, wv = t >> 6;
  const int wm = (wv & 1) * 32, wn = (wv >> 1) * 32;
  const int fr = lane & 15, lk = (lane >> 4) * 8;
  const int sr = t >> 2, sk = (t & 3) * 16;

  const __bf16* Ar = A + (size_t)(m0 + sr) * K + sk;
  const __bf16* Br = B + (size_t)(n0 + sr) * K + sk;

  bf16x8 ra0 = *(const bf16x8*)(Ar);
  bf16x8 ra1 = *(const bf16x8*)(Ar + 8);
  bf16x8 rb0 = *(const bf16x8*)(Br);
  bf16x8 rb1 = *(const bf16x8*)(Br + 8);

  const int nIter = K >> 6;
  int p = 0;
  for (int it = 0; it < nIter; ++it) {
    *(bf16x8*)&Al[p][sr][sk]     = ra0;
    *(bf16x8*)&Al[p][sr][sk + 8] = ra1;
    *(bf16x8*)&Bl[p][sr][sk]     = rb0;
    *(bf16x8*)&Bl[p][sr][sk + 8] = rb1;
    __syncthreads();
    if (it + 1 < nIter) {
      const __bf16* An = Ar + (size_t)(it + 1) * 64;
      const __bf16* Bn = Br + (size_t)(it + 1) * 64;
      ra0 = *(const bf16x8*)(An);
      ra1 = *(const bf16x8*)(An + 8);
      rb0 = *(const bf16x8*)(Bn);
      rb1 = *(const bf16x8*)(Bn + 8);
    }
#pragma unroll
    for (int kk = 0; kk < 64; kk += 32) {
      bf16x8 a0 = *(const bf16x8*)&Al[p][wm + fr][kk + lk];
      bf16x8 a1 = *(const bf16x8*)&Al[p][wm + 16 + fr][kk + lk];
      bf16x8 b0 = *(const bf16x8*)&Bl[p][wn + fr][kk + lk];
      bf16x8 b1 = *(const bf16x8*)&Bl[p][wn + 16 + fr][kk + lk];
      acc[0][0] = __builtin_amdgcn_mfma_f32_16x16x32_bf16(a0, b0, acc[0][0], 0, 0, 0);
      acc[0][1] = __builtin_amdgcn_mfma_f32_16x16x32_bf16(a0, b1, acc[0][1], 0, 0, 0);
      acc[1][0] = __builtin_amdgcn_mfma_f32_16x16x32_bf16(a1, b0, acc[1][0], 0, 0, 0);
      acc[1][1] = __builtin_amdgcn_mfma_f32_16x16x32_bf16(a1, b1, acc[1][1], 0, 0, 0);
    }
    __syncthreads();
    p ^= 1;
  }
}

__device__ __forceinline__ void store_bf16(
    __bf16* dst, int ldst, const f32x4 acc[2][2],
    int m0, int n0, int wm, int wn, int rbase, int fr)
{
#pragma unroll
  for (int i = 0; i < 2; ++i)
#pragma unroll
    for (int r = 0; r < 4; ++r) {
      int m = m0 + wm + i * 16 + rbase + r;
#pragma unroll
      for (int j = 0; j < 2; ++j) {
        int n = n0 + wn + j * 16 + fr;
        dst[(size_t)m * ldst + n] = (__bf16)acc[i][j][r];
      }
    }
}

#define ZERO_ACC(acc) \
  _Pragma("unroll") for (int i_ = 0; i_ < 2; ++i_) \
  _Pragma("unroll") for (int j_ = 0; j_ < 2; ++j_) \
    acc[i_][j_] = (f32x4){0.f, 0.f, 0.f, 0.f};

// ---------------- P0: S hi/lo ; U ; V ; r finalize ; w2sp -------------------
__global__ __launch_bounds__(256) void p0_k(char* __restrict__ ws)
{
  const int blk = blockIdx.x, t = threadIdx.x;
  __shared__ __attribute__((aligned(16))) __bf16 Al[2][64][72];
  __shared__ __attribute__((aligned(16))) __bf16 Bl[2][64][72];

  const int lane = t & 63, wv = t >> 6;
  const int wm = (wv & 1) * 32, wn = (wv >> 1) * 32;
  const int fr = lane & 15, rbase = (lane >> 4) * 4;

  const __bf16* bsfB = (const __bf16*)(ws + OFF_BSFB);

  if (blk < 64) {
    // S = bsfB . bsfB^T (hi/lo bf16)
    const int b = blk >> 4, tl = blk & 15;
    const int m0 = (tl >> 2) * 64, n0 = (tl & 3) * 64;
    f32x4 acc[2][2]; ZERO_ACC(acc);
    gemm_acc(bsfB + (size_t)b * 262144, bsfB + (size_t)b * 262144,
             1024, m0, n0, Al, Bl, acc);
    __bf16* oh = (__bf16*)(ws + OFF_SBH) + (size_t)b * 65536;
    __bf16* ol = (__bf16*)(ws + OFF_SBL) + (size_t)b * 65536;
#pragma unroll
    for (int i = 0; i < 2; ++i)
#pragma unroll
      for (int r = 0; r < 4; ++r) {
        int m = m0 + wm + i * 16 + rbase + r;
#pragma unroll
        for (int j = 0; j < 2; ++j) {
          int n = n0 + wn + j * 16 + fr;
          float v = acc[i][j][r];
          __bf16 h = (__bf16)v;
          oh[(size_t)m * 256 + n] = h;
          ol[(size_t)m * 256 + n] = (__bf16)(v - (float)h);
        }
      }
  } else if (blk < 80) {
    // U = ow . g_w
    const int tl = blk - 64;
    const int m0 = (tl >> 2) * 64, n0 = (tl & 3) * 64;
    f32x4 acc[2][2]; ZERO_ACC(acc);
    gemm_acc((const __bf16*)(ws + OFF_OWB), (const __bf16*)(ws + OFF_GWT),
             256, m0, n0, Al, Bl, acc);
    store_bf16((__bf16*)(ws + OFF_UB), 256, acc, m0, n0, wm, wn, rbase, fr);
  } else if (blk < 96) {
    // V = ph_w^T . th_w
    const int tl = blk - 80;
    const int m0 = (tl >> 2) * 64, n0 = (tl & 3) * 64;
    f32x4 acc[2][2]; ZERO_ACC(acc);
    gemm_acc((const __bf16*)(ws + OFF_PHT), (const __bf16*)(ws + OFF_THT),
             256, m0, n0, Al, Bl, acc);
    store_bf16((__bf16*)(ws + OFF_VB), 256, acc, m0, n0, wm, wn, rbase, fr);
  } else if (blk == 96) {
    // r finalize
    const float* rpart = (const float*)(ws + OFF_RPART);
    float* Rr = (float*)(ws + OFF_R);
#pragma unroll
    for (int j2 = 0; j2 < 4; ++j2) {
      int idx = t + j2 * 256;
      float s = 0.f;
#pragma unroll
      for (int k = 0; k < 16; ++k) s += rpart[k * 1024 + idx];
      Rr[idx] = s;
    }
  } else {
    // w2sp[b][j] = sum_c w2[c] * bsf[b][c][j]   (coalesced over j)
    const int q = blk - 97;              // 0..15
    const int b = q >> 2, seg = (q & 3) * 256;
    const float* w2f = (const float*)(ws + OFF_W2);
    const float* bsf = (const float*)(ws + OFF_BSF);
    float* w2sp = (float*)(ws + OFF_W2SP);
    float acc = 0.f;
#pragma unroll 8
    for (int c = 0; c < 256; ++c)
      acc += w2f[c] * bsf[((size_t)(b * 256 + c)) * 1024 + seg + t];
    w2sp[b * 1024 + seg + t] = acc;
  }
}

// ---------------- P1: T0' ; Yt ; cvec ; qv ----------------------------------
__global__ __launch_bounds__(256) void p1_k(char* __restrict__ ws,
                                            const float* __restrict__ ow_b)
{
  const int blk = blockIdx.x, t = threadIdx.x;
  __shared__ __attribute__((aligned(16))) __bf16 Al[2][64][72];
  __shared__ __attribute__((aligned(16))) __bf16 Bl[2][64][72];
  float* shf = (float*)(&Al[0][0][0]);

  const int lane = t & 63, wv = t >> 6;
  const int wm = (wv & 1) * 32, wn = (wv >> 1) * 32;
  const int fr = lane & 15, rbase = (lane >> 4) * 4;

  const __bf16* UB = (const __bf16*)(ws + OFF_UB);
  const float* Rr  = (const float*)(ws + OFF_R);
  const float* uv  = (const float*)(ws + OFF_UV);

  if (blk < 64) {
    // T0' = U*(Shi+Slo) + uv . r^T
    const int b = blk >> 4, tl = blk & 15;
    const int m0 = (tl >> 2) * 64, n0 = (tl & 3) * 64;
    f32x4 acc[2][2]; ZERO_ACC(acc);
    gemm_acc(UB, (const __bf16*)(ws + OFF_SBH) + (size_t)b * 65536,
             256, m0, n0, Al, Bl, acc);
    gemm_acc(UB, (const __bf16*)(ws + OFF_SBL) + (size_t)b * 65536,
             256, m0, n0, Al, Bl, acc);
    shf[t] = Rr[b * 256 + t];
    __syncthreads();
    __bf16* od = (__bf16*)(ws + OFF_T0) + (size_t)b * 65536;
#pragma unroll
    for (int i = 0; i < 2; ++i)
#pragma unroll
      for (int r = 0; r < 4; ++r) {
        int m = m0 + wm + i * 16 + rbase + r;
        float uvm = uv[m];
#pragma unroll
        for (int j = 0; j < 2; ++j) {
          int n = n0 + wn + j * 16 + fr;
          od[(size_t)m * 256 + n] = (__bf16)(acc[i][j][r] + uvm * shf[n]);
        }
      }
  } else if (blk < 320) {
    // Yt[j][c] = sum_c' bsfT[j][c'] * V[c][c']   (A=bsfT, B=V)
    const int q = blk - 64;
    const int b = q >> 6, tl = q & 63;
    const int m0 = (tl >> 2) * 64, n0 = (tl & 3) * 64;   // m: spatial, n: chan
    f32x4 acc[2][2]; ZERO_ACC(acc);
    gemm_acc((const __bf16*)(ws + OFF_BSFT) + (size_t)b * 262144,
             (const __bf16*)(ws + OFF_VB), 256, m0, n0, Al, Bl, acc);
    store_bf16((__bf16*)(ws + OFF_YT) + (size_t)b * 262144, 256, acc,
               m0, n0, wm, wn, rbase, fr);
  } else if (blk < 336) {
    // cvec = U . r
    const int q = blk - 320;
    const int b = q >> 2, r0 = (q & 3) * 64;
    float* cvec = (float*)(ws + OFF_CVEC);
    shf[t] = Rr[b * 256 + t];
    __syncthreads();
    for (int rr = 0; rr < 16; ++rr) {
      int row = r0 + wv * 16 + rr;
      const __bf16* p = UB + (size_t)row * 256;
      float pa = (float)p[lane] * shf[lane] + (float)p[64 + lane] * shf[64 + lane]
               + (float)p[128 + lane] * shf[128 + lane]
               + (float)p[192 + lane] * shf[192 + lane];
#pragma unroll
      for (int off = 32; off; off >>= 1) pa += __shfl_down(pa, off);
      if (lane == 0) cvec[b * 256 + row] = pa;
    }
  } else {
    // qv = U*(S*v2 + s2*r)/N + uv*(r.v2/N + s2) + ow_b
    const int b = blk - 336;
    float* sv2 = shf;
    float* srr = shf + 256;
    float* sh  = shf + 512;
    float* srv = shf + 768;
    sv2[t] = ((const float*)(ws + OFF_V2))[t];
    srr[t] = Rr[b * 256 + t];
    __syncthreads();
    const float s2v = ((const float*)(ws + OFF_S2))[0];
    if (wv == 0) {
      float pa = srr[lane] * sv2[lane] + srr[64 + lane] * sv2[64 + lane]
               + srr[128 + lane] * sv2[128 + lane] + srr[192 + lane] * sv2[192 + lane];
#pragma unroll
      for (int off = 32; off; off >>= 1) pa += __shfl_down(pa, off);
      if (lane == 0) srv[0] = pa;
    }
    const __bf16* sbh = (const __bf16*)(ws + OFF_SBH) + (size_t)b * 65536;
    const __bf16* sbl = (const __bf16*)(ws + OFF_SBL) + (size_t)b * 65536;
    for (int rr = 0; rr < 64; ++rr) {
      int row = wv * 64 + rr;
      const __bf16* ph_ = sbh + (size_t)row * 256;
      const __bf16* pl_ = sbl + (size_t)row * 256;
      float pa = ((float)ph_[lane] + (float)pl_[lane]) * sv2[lane]
               + ((float)ph_[64 + lane] + (float)pl_[64 + lane]) * sv2[64 + lane]
               + ((float)ph_[128 + lane] + (float)pl_[128 + lane]) * sv2[128 + lane]
               + ((float)ph_[192 + lane] + (float)pl_[192 + lane]) * sv2[192 + lane];
#pragma unroll
      for (int off = 32; off; off >>= 1) pa += __shfl_down(pa, off);
      if (lane == 0) sh[row] = pa + s2v * srr[row];
    }
    __syncthreads();
    float* qv = (float*)(ws + OFF_QV);
    const float rv2 = srv[0];
    for (int rr = 0; rr < 64; ++rr) {
      int row = wv * 64 + rr;
      const __bf16* pu = UB + (size_t)row * 256;
      float pa = (float)pu[lane] * sh[lane] + (float)pu[64 + lane] * sh[64 + lane]
               + (float)pu[128 + lane] * sh[128 + lane]
               + (float)pu[192 + lane] * sh[192 + lane];
#pragma unroll
      for (int off = 32; off; off >>= 1) pa += __shfl_down(pa, off);
      if (lane == 0)
        qv[b * 256 + row] = pa * (1.f / 1024.f)
                          + uv[row] * (rv2 * (1.f / 1024.f) + s2v)
                          + ow_b[row];
    }
  }
}

// ---------------- P2: z = T0'*Yt^T/N + coef.w2sp + qv ; GN raw stats --------
__global__ __launch_bounds__(256) void p2_k(char* __restrict__ ws)
{
  const int blk = blockIdx.x, t = threadIdx.x;
  __shared__ __attribute__((aligned(16))) __bf16 Al[2][64][72];
  __shared__ __attribute__((aligned(16))) __bf16 Bl[2][64][72];
  float* shf = (float*)(&Al[0][0][0]);

  const int lane = t & 63, wv = t >> 6;
  const int wm = (wv & 1) * 32, wn = (wv >> 1) * 32;
  const int fr = lane & 15, rbase = (lane >> 4) * 4;

  const int b = blk >> 6, t6 = blk & 63;
  const int mt = t6 >> 4, nt = t6 & 15;
  const int m0 = mt * 64, n0 = nt * 64;
  (void)nt;

  f32x4 acc[2][2]; ZERO_ACC(acc);
  gemm_acc((const __bf16*)(ws + OFF_T0) + (size_t)b * 65536,
           (const __bf16*)(ws + OFF_YT) + (size_t)b * 262144,
           256, m0, n0, Al, Bl, acc);

  const float* uv   = (const float*)(ws + OFF_UV);
  const float* cvec = (const float*)(ws + OFF_CVEC);
  const float* qv   = (const float*)(ws + OFF_QV);
  const float* w2sp = (const float*)(ws + OFF_W2SP);
  float* SRAW = (float*)(ws + OFF_STATS);
  float* zb = (float*)(ws + OFF_Z) + (size_t)b * 262144;

  float gs[2] = {0.f, 0.f}, gq[2] = {0.f, 0.f};
  int gidx[2];
  const float s1024 = 1.f / 1024.f;
#pragma unroll
  for (int i = 0; i < 2; ++i) {
    gidx[i] = (wm + i * 16 + rbase) >> 3;
#pragma unroll
    for (int r = 0; r < 4; ++r) {
      int m = m0 + wm + i * 16 + rbase + r;
      float qm = qv[b * 256 + m];
      float coefm = uv[m] + cvec[b * 256 + m] * s1024;
#pragma unroll
      for (int j = 0; j < 2; ++j) {
        int n = n0 + wn + j * 16 + fr;
        float v = acc[i][j][r] * s1024 + coefm * w2sp[b * 1024 + n] + qm;
        zb[(size_t)m * 1024 + n] = v;
        gs[i] += v;
        gq[i] += v * v;
      }
    }
  }
  __syncthreads();
  if (t < 16) shf[t] = 0.f;
  __syncthreads();
#pragma unroll
  for (int i = 0; i < 2; ++i) {
    atomicAdd(&shf[gidx[i] * 2], gs[i]);
    atomicAdd(&shf[gidx[i] * 2 + 1], gq[i]);
  }
  __syncthreads();
  if (t < 16) {
    int g = mt * 8 + (t >> 1);
    atomicAdd(&SRAW[(b * 32 + g) * 2 + (t & 1)], shf[t]);
  }
}

// ---------------- fused GN + residual scatter (float4) ----------------------
__device__ __forceinline__ float4 gmix(float4 bz, float4 zz, float a, float c)
{
  float4 r;
  r.x = bz.x + zz.x * a + c;
  r.y = bz.y + zz.y * a + c;
  r.z = bz.z + zz.z * a + c;
  r.w = bz.w + zz.w * a + c;
  return r;
}
__device__ __forceinline__ float max4(float4 v)
{ return fmaxf(fmaxf(v.x, v.y), fmaxf(v.z, v.w)); }

// raw (sum, sumsq) -> (a = inv*gamma, c0 = beta - mean*a)
__device__ __forceinline__ void gn_coeff(const float2* __restrict__ ST,
                                         const float* __restrict__ gamma,
                                         const float* __restrict__ beta,
                                         int b, int ch, float& a, float& c0)
{
  float2 sq = ST[b * 32 + (ch >> 3)];
  float mean = sq.x * (1.0f / 8192.0f);
  float var  = sq.y * (1.0f / 8192.0f) - mean * mean;
  float inv  = rsqrtf(var + 1e-5f);
  a  = inv * gamma[ch];
  c0 = beta[ch] - mean * a;
}

__global__ __launch_bounds__(256) void scat_k(
    const char* __restrict__ ws,
    const float* __restrict__ f0, const float* __restrict__ f1,
    const float* __restrict__ f2, const float* __restrict__ f3,
    const float* __restrict__ f4,
    const float* __restrict__ gamma, const float* __restrict__ beta,
    float* __restrict__ out)
{
  const float* Z = (const float*)(ws + OFF_Z);
  const float* BSF = (const float*)(ws + OFF_BSF);
  const float2* ST = (const float2*)(ws + OFF_STATS);
  const int i4 = blockIdx.x * 256 + threadIdx.x;

  if (i4 < 4194304) {                       // f0: 128x128, upsample x4
    const int l = i4 << 2;
    const int x = l & 127, yy = (l >> 7) & 127, nc = l >> 14;
    const int ch = nc & 255, b = nc >> 8;
    float a, c0; gn_coeff(ST, gamma, beta, b, ch, a, c0);
    size_t base = (size_t)nc * 1024 + ((yy >> 2) << 5) + (x >> 2);
    float v = BSF[base] + Z[base] * a + c0;
    float4 f = ((const float4*)f0)[i4];
    float4 o; o.x = f.x + v; o.y = f.y + v; o.z = f.z + v; o.w = f.w + v;
    ((float4*)out)[i4] = o;
  } else if (i4 < 5242880) {                // f1: 64x64, upsample x2
    const int l4 = i4 - 4194304;
    const int l = l4 << 2;
    const int x = l & 63, yy = (l >> 6) & 63, nc = l >> 12;
    const int ch = nc & 255, b = nc >> 8;
    float a, c0; gn_coeff(ST, gamma, beta, b, ch, a, c0);
    size_t base = (size_t)nc * 1024 + ((yy >> 1) << 5) + (x >> 1);
    float v0 = BSF[base] + Z[base] * a + c0;
    float v1 = BSF[base + 1] + Z[base + 1] * a + c0;
    float4 f = ((const float4*)f1)[l4];
    float4 o; o.x = f.x + v0; o.y = f.y + v0; o.z = f.z + v1; o.w = f.w + v1;
    ((float4*)out)[i4] = o;
  } else if (i4 < 5505024) {                // f2: 32x32, identity
    const int l4 = i4 - 5242880;
    const int l = l4 << 2;
    const int nc = l >> 10, e = l & 1023;
    const int ch = nc & 255, b = nc >> 8;
    float a, c0; gn_coeff(ST, gamma, beta, b, ch, a, c0);
    size_t base = (size_t)nc * 1024 + e;
    float4 z4 = *(const float4*)&Z[base];
    float4 b4 = *(const float4*)&BSF[base];
    float4 v = gmix(b4, z4, a, c0);
    float4 f = ((const float4*)f2)[l4];
    float4 o; o.x = f.x + v.x; o.y = f.y + v.y; o.z = f.z + v.z; o.w = f.w + v.w;
    ((float4*)out)[i4] = o;
  } else if (i4 < 5570560) {                // f3: 16x16, maxpool 2x2
    const int l4 = i4 - 5505024;
    const int l = l4 << 2;
    const int x = l & 15, yy = (l >> 4) & 15, nc = l >> 8;
    const int ch = nc & 255, b = nc >> 8;
    float a, c0; gn_coeff(ST, gamma, beta, b, ch, a, c0);
    size_t base = (size_t)nc * 1024;
    const int p0 = (yy * 2) * 32 + (x * 2);
    float4 r0a = gmix(*(const float4*)&BSF[base + p0],      *(const float4*)&Z[base + p0],      a, c0);
    float4 r0b = gmix(*(const float4*)&BSF[base + p0 + 4],  *(const float4*)&Z[base + p0 + 4],  a, c0);
    float4 r1a = gmix(*(const float4*)&BSF[base + p0 + 32], *(const float4*)&Z[base + p0 + 32], a, c0);
    float4 r1b = gmix(*(const float4*)&BSF[base + p0 + 36], *(const float4*)&Z[base + p0 + 36], a, c0);
    float4 f = ((const float4*)f3)[l4];
    float4 o;
    o.x = f.x + fmaxf(fmaxf(r0a.x, r0a.y), fmaxf(r1a.x, r1a.y));
    o.y = f.y + fmaxf(fmaxf(r0a.z, r0a.w), fmaxf(r1a.z, r1a.w));
    o.z = f.z + fmaxf(fmaxf(r0b.x, r0b.y), fmaxf(r1b.x, r1b.y));
    o.w = f.w + fmaxf(fmaxf(r0b.z, r0b.w), fmaxf(r1b.z, r1b.w));
    ((float4*)out)[i4] = o;
  } else {                                   // f4: 8x8, maxpool 4x4
    const int l4 = i4 - 5570560;
    const int l = l4 << 2;
    const int x = l & 7, yy = (l >> 3) & 7, nc = l >> 6;
    const int ch = nc & 255, b = nc >> 8;
    float a, c0; gn_coeff(ST, gamma, beta, b, ch, a, c0);
    size_t base = (size_t)nc * 1024;
    float4 mx = {-3.4e38f, -3.4e38f, -3.4e38f, -3.4e38f};
#pragma unroll
    for (int r = 0; r < 4; ++r) {
      const float* zp = &Z[base + (size_t)(yy * 4 + r) * 32 + x * 4];
      const float* bp = &BSF[base + (size_t)(yy * 4 + r) * 32 + x * 4];
      float4 q0 = gmix(*(const float4*)(bp),      *(const float4*)(zp),      a, c0);
      float4 q1 = gmix(*(const float4*)(bp + 4),  *(const float4*)(zp + 4),  a, c0);
      float4 q2 = gmix(*(const float4*)(bp + 8),  *(const float4*)(zp + 8),  a, c0);
      float4 q3 = gmix(*(const float4*)(bp + 12), *(const float4*)(zp + 12), a, c0);
      mx.x = fmaxf(mx.x, max4(q0));
      mx.y = fmaxf(mx.y, max4(q1));
      mx.z = fmaxf(mx.z, max4(q2));
      mx.w = fmaxf(mx.w, max4(q3));
    }
    float4 f = ((const float4*)f4)[l4];
    float4 o; o.x = f.x + mx.x; o.y = f.y + mx.y; o.z = f.z + mx.z; o.w = f.w + mx.w;
    ((float4*)out)[i4] = o;
  }
}

// ---------------------------------------------------------------------------
extern "C" void kernel_launch(void* const* d_in, const int* in_sizes, int n_in,
                              void* d_out, int out_size, void* d_ws, size_t ws_size,
                              hipStream_t stream)
{
  (void)in_sizes; (void)n_in; (void)out_size; (void)ws_size;
  const float* f0   = (const float*)d_in[0];
  const float* f1   = (const float*)d_in[1];
  const float* f2   = (const float*)d_in[2];
  const float* f3   = (const float*)d_in[3];
  const float* f4   = (const float*)d_in[4];
  const float* g_w  = (const float*)d_in[5];
  const float* g_b  = (const float*)d_in[6];
  const float* th_w = (const float*)d_in[7];
  const float* th_b = (const float*)d_in[8];
  const float* ph_w = (const float*)d_in[9];
  const float* ph_b = (const float*)d_in[10];
  const float* ow_w = (const float*)d_in[11];
  const float* ow_b = (const float*)d_in[12];
  const float* gn_g = (const float*)d_in[13];
  const float* gn_b = (const float*)d_in[14];
  char* ws = (char*)d_ws;

  // 1) gather + weight prep
  prep_k<<<311, 256, 0, stream>>>(f0, f1, f2, f3, f4,
                                  g_w, ph_w, th_w, ow_w,
                                  g_b, ph_b, th_b, ws);
  // 2) S (hi/lo) ; U ; V ; r ; w2sp
  p0_k<<<113, 256, 0, stream>>>(ws);
  // 3) T0' ; Yt ; cvec ; qv
  p1_k<<<340, 256, 0, stream>>>(ws, ow_b);
  // 4) z + GN raw stats
  p2_k<<<256, 256, 0, stream>>>(ws);
  // 5) fused GN-normalize + residual scatter
  scat_k<<<21824, 256, 0, stream>>>(ws, f0, f1, f2, f3, f4, gn_g, gn_b,
                                    (float*)d_out);
}

// Round 6
// 87.839 us; speedup vs baseline: 1.9259x; 1.9259x over previous
//
#include <hip/hip_runtime.h>

typedef __bf16 bf16x8 __attribute__((ext_vector_type(8)));
typedef float f32x4 __attribute__((ext_vector_type(4)));

// ---------------------------------------------------------------------------
// Workspace layout (bytes):
#define OFF_BSF   0x000000   // f32  [4][256][1024]  4 MB
#define OFF_BSFT  0x400000   // bf16 [4][1024][256]  2 MB   (spatial-major)
#define OFF_BSFB  0x600000   // bf16 [4][256][1024]  2 MB   (ch-major; reused as Yt in P1+)
#define OFF_YT    0x600000   // bf16 [4][1024][256]  2 MB   Yt[j][c] = (V.bsf)^T + v2[c]
#define OFF_Z     0x800000   // f32  [4][256][1024]  4 MB
#define OFF_SBH   0xC00000   // bf16 [4][256][256]   512 KB  S hi
#define OFF_SBL   0xC80000   // bf16 [4][256][256]   512 KB  S lo (residual)
#define OFF_T0    0xD00000   // bf16 [4][256][256]   T0' = U*S + uv*r^T
#define OFF_OWB   0xE00000   // bf16 [256][256]
#define OFF_GWT   0xE20000   // bf16 g_w^T
#define OFF_PHT   0xE40000   // bf16 ph_w^T
#define OFF_THT   0xE60000   // bf16 th_w^T
#define OFF_UB    0xE80000   // bf16 U = ow*g_w
#define OFF_VB    0xEA0000   // bf16 V = ph_w^T*th_w
#define OFF_UT    0xEC0000   // bf16 U^T
#define OFF_RPART 0xEE0000   // f32 [16][1024] row-sum partials
#define OFF_R     0xEF0000   // f32 [4][256]  r = bsf.1
#define OFF_UV    0xEF1000   // f32 [256]  u = ow*g_b
#define OFF_V2P   0xEF1400   // f32 [4][256]  v2 partials (v2 = ph_w^T*th_b)
#define OFF_W2P   0xEF2400   // f32 [4][256]  w2 partials (w2 = th_w^T*ph_b)
#define OFF_S2    0xEF3400   // f32 s2 = ph_b.th_b
#define OFF_CVEC  0xEF4000   // f32 [4][256]  U*r  (atomic-accumulated)
#define OFF_STATS 0xEF9000   // f32 [4][32][2] RAW (sum, sumsq) via atomics
#define OFF_W2SP  0xEFA000   // f32 [2][4][1024] w2sp partials (w2^T . bsf)
// ---------------------------------------------------------------------------

// ---------------- prep: gather + weight cvt/transpose + bias matvecs --------
// Round-5 lesson: serial wave-per-row matvec loops (64 dependent iterations of
// scalar loads + shfl chains) straggle 20-70us at ~1% occupancy while every
// GEMM block finishes in ~5us. All small matvecs are now chunked-parallel
// coalesced column reductions; nothing in any launch runs >128 serial
// latency-bound iterations.
__global__ __launch_bounds__(256) void prep_k(
    const float* __restrict__ f0, const float* __restrict__ f1,
    const float* __restrict__ f2, const float* __restrict__ f3,
    const float* __restrict__ f4,
    const float* __restrict__ g_w, const float* __restrict__ ph_w,
    const float* __restrict__ th_w, const float* __restrict__ ow_w,
    const float* __restrict__ g_b, const float* __restrict__ ph_b,
    const float* __restrict__ th_b,
    char* __restrict__ ws)
{
  const int blk = blockIdx.x, t = threadIdx.x;
  __shared__ __attribute__((aligned(16))) union {
    __bf16 Lt[64][66];
    __bf16 T[64][72];
    float vec2[544];
  } sm;

  if (blk < 256) {
    // ---- gather: bsf fp32 + bsfB bf16 (ch-major) + bsfT bf16 (sp-major) + rowsum partials
    float*  bsf   = (float*)(ws + OFF_BSF);
    __bf16* bsfT  = (__bf16*)(ws + OFF_BSFT);
    __bf16* bsfB  = (__bf16*)(ws + OFF_BSFB);
    float*  rpart = (float*)(ws + OFF_RPART);
    const int sblk = blk & 15, cblk = (blk >> 4) & 3, b = blk >> 6;
    const int c0 = cblk * 64, s0 = sblk * 64;
    const int spl = t & 63, sp = s0 + spl;
    const int y = sp >> 5, x = sp & 31;
#pragma unroll
    for (int i = 0; i < 16; ++i) {
      const int cl = (t >> 6) + i * 4;
      const int nc = b * 256 + c0 + cl;

      const float* p0 = f0 + (size_t)nc * 16384 + (y * 4) * 128 + x * 4;
      float4 r0 = *(const float4*)(p0);
      float4 r1 = *(const float4*)(p0 + 128);
      float4 r2 = *(const float4*)(p0 + 256);
      float4 r3 = *(const float4*)(p0 + 384);
      float a  = fmaxf(fmaxf(r0.x, r0.y), fmaxf(r0.z, r0.w));
      float bb = fmaxf(fmaxf(r1.x, r1.y), fmaxf(r1.z, r1.w));
      float c  = fmaxf(fmaxf(r2.x, r2.y), fmaxf(r2.z, r2.w));
      float d  = fmaxf(fmaxf(r3.x, r3.y), fmaxf(r3.z, r3.w));
      float m0v = fmaxf(fmaxf(a, bb), fmaxf(c, d));

      const float* p1 = f1 + (size_t)nc * 4096 + (y * 2) * 64 + x * 2;
      float2 s0v = *(const float2*)(p1);
      float2 s1v = *(const float2*)(p1 + 64);
      float m1v = fmaxf(fmaxf(s0v.x, s0v.y), fmaxf(s1v.x, s1v.y));

      float v2 = f2[(size_t)nc * 1024 + sp];
      float v3 = f3[(size_t)nc * 256 + (y >> 1) * 16 + (x >> 1)];
      float v4 = f4[(size_t)nc * 64  + (y >> 2) * 8  + (x >> 2)];
      float val = (m0v + m1v + v2 + v3 + v4) * 0.2f;
      bsf[(size_t)nc * 1024 + sp]  = val;
      bsfB[(size_t)nc * 1024 + sp] = (__bf16)val;
      sm.Lt[cl][spl] = (__bf16)val;
      float rs = val;
#pragma unroll
      for (int off = 32; off; off >>= 1) rs += __shfl_down(rs, off);
      if (spl == 0) rpart[sblk * 1024 + nc] = rs;
    }
    __syncthreads();
#pragma unroll
    for (int i = 0; i < 16; ++i) {
      int linear = t + i * 256;
      int spl2 = linear >> 6, cl2 = linear & 63;
      bsfT[((size_t)b * 1024 + s0 + spl2) * 256 + c0 + cl2] = sm.Lt[cl2][spl2];
    }
  } else if (blk < 304) {
    // ---- weight transposes (fp32 -> bf16): gwT/phT/thT, 64x64 tiles
    const int w = (blk - 256) >> 4, tl = (blk - 256) & 15;
    const float* src = (w == 0) ? g_w : (w == 1) ? ph_w : th_w;
    __bf16* dst = (__bf16*)(ws + ((w == 0) ? OFF_GWT : (w == 1) ? OFF_PHT : OFF_THT));
    const int ti = (tl >> 2) * 64, tj = (tl & 3) * 64;
#pragma unroll
    for (int i = 0; i < 4; ++i) {
      int idx = i * 256 + t;
      int r = idx >> 4, c4 = (idx & 15) << 2;
      float4 v = *(const float4*)&src[(size_t)(ti + r) * 256 + tj + c4];
      sm.T[c4 + 0][r] = (__bf16)v.x;
      sm.T[c4 + 1][r] = (__bf16)v.y;
      sm.T[c4 + 2][r] = (__bf16)v.z;
      sm.T[c4 + 3][r] = (__bf16)v.w;
    }
    __syncthreads();
#pragma unroll
    for (int i = 0; i < 2; ++i) {
      int idx = i * 256 + t;
      int aa = idx >> 3, cc = (idx & 7) << 3;
      bf16x8 o = *(const bf16x8*)&sm.T[aa][cc];
      *(bf16x8*)&dst[(size_t)(tj + aa) * 256 + ti + cc] = o;
    }
  } else if (blk < 308) {
    // ---- owB plain convert
    const int r0 = (blk - 304) * 64;
    __bf16* owB = (__bf16*)(ws + OFF_OWB);
#pragma unroll
    for (int i = 0; i < 8; ++i) {
      int lin = i * 2048 + t * 8;
      size_t gidx = (size_t)r0 * 256 + lin;
      float4 v0 = *(const float4*)&ow_w[gidx];
      float4 v1 = *(const float4*)&ow_w[gidx + 4];
      bf16x8 o;
      o[0] = (__bf16)v0.x; o[1] = (__bf16)v0.y; o[2] = (__bf16)v0.z; o[3] = (__bf16)v0.w;
      o[4] = (__bf16)v1.x; o[5] = (__bf16)v1.y; o[6] = (__bf16)v1.z; o[7] = (__bf16)v1.w;
      *(bf16x8*)&owB[gidx] = o;
    }
  } else if (blk < 324) {
    // ---- uv = ow_w . g_b : 16 blocks x 16 rows, LDS tile reduction
    const int q = blk - 308;
    const int r0 = q * 16;
    float* uv = (float*)(ws + OFF_UV);
    sm.vec2[t] = g_b[t];
    __syncthreads();
    const int rl = t >> 4;             // 0..15 local row
    const int ci = (t & 15) * 16;      // column chunk start
    const float* p = ow_w + (size_t)(r0 + rl) * 256 + ci;
    float acc = 0.f;
#pragma unroll
    for (int u = 0; u < 4; ++u) {
      float4 v = *(const float4*)(p + u * 4);
      acc += v.x * sm.vec2[ci + u * 4]     + v.y * sm.vec2[ci + u * 4 + 1]
           + v.z * sm.vec2[ci + u * 4 + 2] + v.w * sm.vec2[ci + u * 4 + 3];
    }
    __syncthreads();
    sm.vec2[256 + rl * 17 + (t & 15)] = acc;
    __syncthreads();
    if (t < 16) {
      float s = 0.f;
#pragma unroll
      for (int i = 0; i < 16; ++i) s += sm.vec2[256 + t * 17 + i];
      uv[r0 + t] = s;
    }
  } else if (blk < 328) {
    // ---- v2 partials: v2part[q][t] = sum_{c in chunk q} ph_w[c][t]*th_b[c]
    const int q = blk - 324, c0 = q * 64;
    float* v2p = (float*)(ws + OFF_V2P);
    if (t < 64) sm.vec2[t] = th_b[c0 + t];
    __syncthreads();
    float acc = 0.f;
#pragma unroll 8
    for (int c = 0; c < 64; ++c)
      acc += ph_w[(size_t)(c0 + c) * 256 + t] * sm.vec2[c];
    v2p[q * 256 + t] = acc;
  } else if (blk < 332) {
    // ---- w2 partials: w2part[q][t] = sum_{c in chunk q} th_w[c][t]*ph_b[c]
    const int q = blk - 328, c0 = q * 64;
    float* w2p = (float*)(ws + OFF_W2P);
    if (t < 64) sm.vec2[t] = ph_b[c0 + t];
    __syncthreads();
    float acc = 0.f;
#pragma unroll 8
    for (int c = 0; c < 64; ++c)
      acc += th_w[(size_t)(c0 + c) * 256 + t] * sm.vec2[c];
    w2p[q * 256 + t] = acc;
  } else if (blk == 332) {
    // ---- s2 = ph_b.th_b ; zero raw GN stats
    float* s2 = (float*)(ws + OFF_S2);
    if (t < 64) {
      float pa = ph_b[t] * th_b[t] + ph_b[64 + t] * th_b[64 + t]
               + ph_b[128 + t] * th_b[128 + t] + ph_b[192 + t] * th_b[192 + t];
#pragma unroll
      for (int off = 32; off; off >>= 1) pa += __shfl_down(pa, off);
      if (t == 0) s2[0] = pa;
    }
    ((float*)(ws + OFF_STATS))[t] = 0.f;
  } else {
    // ---- zero cvec accumulator
    float* cvec = (float*)(ws + OFF_CVEC);
#pragma unroll
    for (int i = 0; i < 4; ++i) cvec[i * 256 + t] = 0.f;
  }
}

// ---------------- GEMM accumulate core (64x64 tile, 4 waves, dbuf) ----------
__device__ __forceinline__ void gemm_acc(
    const __bf16* __restrict__ A, const __bf16* __restrict__ B,
    const int K, const int m0, const int n0,
    __bf16 (*Al)[64][72], __bf16 (*Bl)[64][72],
    f32x4 acc[2][2])
{
  const int t = threadIdx.x;
  const int lane = t & 63, wv = t >> 6;
  const int wm = (wv & 1) * 32, wn = (wv >> 1) * 32;
  const int fr = lane & 15, lk = (lane >> 4) * 8;
  const int sr = t >> 2, sk = (t & 3) * 16;

  const __bf16* Ar = A + (size_t)(m0 + sr) * K + sk;
  const __bf16* Br = B + (size_t)(n0 + sr) * K + sk;

  bf16x8 ra0 = *(const bf16x8*)(Ar);
  bf16x8 ra1 = *(const bf16x8*)(Ar + 8);
  bf16x8 rb0 = *(const bf16x8*)(Br);
  bf16x8 rb1 = *(const bf16x8*)(Br + 8);

  const int nIter = K >> 6;
  int p = 0;
  for (int it = 0; it < nIter; ++it) {
    *(bf16x8*)&Al[p][sr][sk]     = ra0;
    *(bf16x8*)&Al[p][sr][sk + 8] = ra1;
    *(bf16x8*)&Bl[p][sr][sk]     = rb0;
    *(bf16x8*)&Bl[p][sr][sk + 8] = rb1;
    __syncthreads();
    if (it + 1 < nIter) {
      const __bf16* An = Ar + (size_t)(it + 1) * 64;
      const __bf16* Bn = Br + (size_t)(it + 1) * 64;
      ra0 = *(const bf16x8*)(An);
      ra1 = *(const bf16x8*)(An + 8);
      rb0 = *(const bf16x8*)(Bn);
      rb1 = *(const bf16x8*)(Bn + 8);
    }
#pragma unroll
    for (int kk = 0; kk < 64; kk += 32) {
      bf16x8 a0 = *(const bf16x8*)&Al[p][wm + fr][kk + lk];
      bf16x8 a1 = *(const bf16x8*)&Al[p][wm + 16 + fr][kk + lk];
      bf16x8 b0 = *(const bf16x8*)&Bl[p][wn + fr][kk + lk];
      bf16x8 b1 = *(const bf16x8*)&Bl[p][wn + 16 + fr][kk + lk];
      acc[0][0] = __builtin_amdgcn_mfma_f32_16x16x32_bf16(a0, b0, acc[0][0], 0, 0, 0);
      acc[0][1] = __builtin_amdgcn_mfma_f32_16x16x32_bf16(a0, b1, acc[0][1], 0, 0, 0);
      acc[1][0] = __builtin_amdgcn_mfma_f32_16x16x32_bf16(a1, b0, acc[1][0], 0, 0, 0);
      acc[1][1] = __builtin_amdgcn_mfma_f32_16x16x32_bf16(a1, b1, acc[1][1], 0, 0, 0);
    }
    __syncthreads();
    p ^= 1;
  }
}

__device__ __forceinline__ void store_bf16(
    __bf16* dst, int ldst, const f32x4 acc[2][2],
    int m0, int n0, int wm, int wn, int rbase, int fr)
{
#pragma unroll
  for (int i = 0; i < 2; ++i)
#pragma unroll
    for (int r = 0; r < 4; ++r) {
      int m = m0 + wm + i * 16 + rbase + r;
#pragma unroll
      for (int j = 0; j < 2; ++j) {
        int n = n0 + wn + j * 16 + fr;
        dst[(size_t)m * ldst + n] = (__bf16)acc[i][j][r];
      }
    }
}

#define ZERO_ACC(acc) \
  _Pragma("unroll") for (int i_ = 0; i_ < 2; ++i_) \
  _Pragma("unroll") for (int j_ = 0; j_ < 2; ++j_) \
    acc[i_][j_] = (f32x4){0.f, 0.f, 0.f, 0.f};

// ---------------- P0: S hi/lo ; U(+UT) ; V ; r finalize ; w2sp parts --------
__global__ __launch_bounds__(256) void p0_k(char* __restrict__ ws)
{
  const int blk = blockIdx.x, t = threadIdx.x;
  __shared__ __attribute__((aligned(16))) __bf16 Al[2][64][72];
  __shared__ __attribute__((aligned(16))) __bf16 Bl[2][64][72];
  float* shf = (float*)(&Al[0][0][0]);

  const int lane = t & 63, wv = t >> 6;
  const int wm = (wv & 1) * 32, wn = (wv >> 1) * 32;
  const int fr = lane & 15, rbase = (lane >> 4) * 4;
  (void)lane; (void)wv;

  const __bf16* bsfB = (const __bf16*)(ws + OFF_BSFB);

  if (blk < 64) {
    // S = bsfB . bsfB^T (hi/lo bf16)
    const int b = blk >> 4, tl = blk & 15;
    const int m0 = (tl >> 2) * 64, n0 = (tl & 3) * 64;
    f32x4 acc[2][2]; ZERO_ACC(acc);
    gemm_acc(bsfB + (size_t)b * 262144, bsfB + (size_t)b * 262144,
             1024, m0, n0, Al, Bl, acc);
    __bf16* oh = (__bf16*)(ws + OFF_SBH) + (size_t)b * 65536;
    __bf16* ol = (__bf16*)(ws + OFF_SBL) + (size_t)b * 65536;
#pragma unroll
    for (int i = 0; i < 2; ++i)
#pragma unroll
      for (int r = 0; r < 4; ++r) {
        int m = m0 + wm + i * 16 + rbase + r;
#pragma unroll
        for (int j = 0; j < 2; ++j) {
          int n = n0 + wn + j * 16 + fr;
          float v = acc[i][j][r];
          __bf16 h = (__bf16)v;
          oh[(size_t)m * 256 + n] = h;
          ol[(size_t)m * 256 + n] = (__bf16)(v - (float)h);
        }
      }
  } else if (blk < 80) {
    // U = ow . g_w  (store U and U^T)
    const int tl = blk - 64;
    const int m0 = (tl >> 2) * 64, n0 = (tl & 3) * 64;
    f32x4 acc[2][2]; ZERO_ACC(acc);
    gemm_acc((const __bf16*)(ws + OFF_OWB), (const __bf16*)(ws + OFF_GWT),
             256, m0, n0, Al, Bl, acc);
    __bf16* ub = (__bf16*)(ws + OFF_UB);
    __bf16* ut = (__bf16*)(ws + OFF_UT);
#pragma unroll
    for (int i = 0; i < 2; ++i)
#pragma unroll
      for (int r = 0; r < 4; ++r) {
        int m = m0 + wm + i * 16 + rbase + r;
#pragma unroll
        for (int j = 0; j < 2; ++j) {
          int n = n0 + wn + j * 16 + fr;
          __bf16 v = (__bf16)acc[i][j][r];
          ub[(size_t)m * 256 + n] = v;
          ut[(size_t)n * 256 + m] = v;
        }
      }
  } else if (blk < 96) {
    // V = ph_w^T . th_w
    const int tl = blk - 80;
    const int m0 = (tl >> 2) * 64, n0 = (tl & 3) * 64;
    f32x4 acc[2][2]; ZERO_ACC(acc);
    gemm_acc((const __bf16*)(ws + OFF_PHT), (const __bf16*)(ws + OFF_THT),
             256, m0, n0, Al, Bl, acc);
    store_bf16((__bf16*)(ws + OFF_VB), 256, acc, m0, n0, wm, wn, rbase, fr);
  } else if (blk == 96) {
    // r finalize
    const float* rpart = (const float*)(ws + OFF_RPART);
    float* Rr = (float*)(ws + OFF_R);
#pragma unroll
    for (int j2 = 0; j2 < 4; ++j2) {
      int idx = t + j2 * 256;
      float s = 0.f;
#pragma unroll
      for (int k = 0; k < 16; ++k) s += rpart[k * 1024 + idx];
      Rr[idx] = s;
    }
  } else {
    // w2sp partials: w2spP[half][b][j] = sum_{c in half} w2[c]*bsf[b][c][j]
    const int q = blk - 97;              // 0..31
    const int half = q >> 4, idx = q & 15;
    const int b = idx >> 2, seg = (idx & 3) * 256;
    const int ch0 = half * 128;
    const float* w2p = (const float*)(ws + OFF_W2P);
    const float* bsf = (const float*)(ws + OFF_BSF);
    float* w2sp = (float*)(ws + OFF_W2SP);
    if (t < 128) {
      int c = ch0 + t;
      shf[t] = w2p[c] + w2p[256 + c] + w2p[512 + c] + w2p[768 + c];
    }
    __syncthreads();
    float acc = 0.f;
#pragma unroll 8
    for (int c = 0; c < 128; ++c)
      acc += shf[c] * bsf[((size_t)(b * 256 + ch0 + c)) * 1024 + seg + t];
    w2sp[half * 4096 + b * 1024 + seg + t] = acc;
  }
}

// ---------------- P1: T0' ; Yt(+v2 fold) ; cvec (chunked atomics) -----------
__global__ __launch_bounds__(256) void p1_k(char* __restrict__ ws)
{
  const int blk = blockIdx.x, t = threadIdx.x;
  __shared__ __attribute__((aligned(16))) __bf16 Al[2][64][72];
  __shared__ __attribute__((aligned(16))) __bf16 Bl[2][64][72];
  float* shf = (float*)(&Al[0][0][0]);

  const int lane = t & 63, wv = t >> 6;
  const int wm = (wv & 1) * 32, wn = (wv >> 1) * 32;
  const int fr = lane & 15, rbase = (lane >> 4) * 4;
  (void)lane; (void)wv;

  const __bf16* UB = (const __bf16*)(ws + OFF_UB);
  const float* Rr  = (const float*)(ws + OFF_R);
  const float* uv  = (const float*)(ws + OFF_UV);

  if (blk < 64) {
    // T0' = U*(Shi+Slo) + uv . r^T
    const int b = blk >> 4, tl = blk & 15;
    const int m0 = (tl >> 2) * 64, n0 = (tl & 3) * 64;
    f32x4 acc[2][2]; ZERO_ACC(acc);
    gemm_acc(UB, (const __bf16*)(ws + OFF_SBH) + (size_t)b * 65536,
             256, m0, n0, Al, Bl, acc);
    gemm_acc(UB, (const __bf16*)(ws + OFF_SBL) + (size_t)b * 65536,
             256, m0, n0, Al, Bl, acc);
    shf[t] = Rr[b * 256 + t];
    __syncthreads();
    __bf16* od = (__bf16*)(ws + OFF_T0) + (size_t)b * 65536;
#pragma unroll
    for (int i = 0; i < 2; ++i)
#pragma unroll
      for (int r = 0; r < 4; ++r) {
        int m = m0 + wm + i * 16 + rbase + r;
        float uvm = uv[m];
#pragma unroll
        for (int j = 0; j < 2; ++j) {
          int n = n0 + wn + j * 16 + fr;
          od[(size_t)m * 256 + n] = (__bf16)(acc[i][j][r] + uvm * shf[n]);
        }
      }
  } else if (blk < 320) {
    // Yt'[j][c] = sum_c' bsfT[j][c'] * V[c][c']  + v2[c]   (v2 fold!)
    const int q = blk - 64;
    const int b = q >> 6, tl = q & 63;
    const int m0 = (tl >> 2) * 64, n0 = (tl & 3) * 64;   // m: spatial, n: chan
    f32x4 acc[2][2]; ZERO_ACC(acc);
    gemm_acc((const __bf16*)(ws + OFF_BSFT) + (size_t)b * 262144,
             (const __bf16*)(ws + OFF_VB), 256, m0, n0, Al, Bl, acc);
    const float* v2p = (const float*)(ws + OFF_V2P);
    shf[t] = v2p[t] + v2p[256 + t] + v2p[512 + t] + v2p[768 + t];
    __syncthreads();
    __bf16* od = (__bf16*)(ws + OFF_YT) + (size_t)b * 262144;
#pragma unroll
    for (int i = 0; i < 2; ++i)
#pragma unroll
      for (int r = 0; r < 4; ++r) {
        int m = m0 + wm + i * 16 + rbase + r;
#pragma unroll
        for (int j = 0; j < 2; ++j) {
          int n = n0 + wn + j * 16 + fr;
          od[(size_t)m * 256 + n] = (__bf16)(acc[i][j][r] + shf[n]);
        }
      }
  } else {
    // cvec[b] += UT-chunk^T . Rr[b]-chunk  (coalesced + f32 atomics)
    const int q = blk - 320;             // 0..15
    const int b = q >> 2, cc = (q & 3) * 64;
    const __bf16* UT = (const __bf16*)(ws + OFF_UT);
    float* cvec = (float*)(ws + OFF_CVEC);
    if (t < 64) shf[t] = Rr[b * 256 + cc + t];
    __syncthreads();
    float acc = 0.f;
#pragma unroll 8
    for (int c = 0; c < 64; ++c)
      acc += (float)UT[(size_t)(cc + c) * 256 + t] * shf[c];
    atomicAdd(&cvec[b * 256 + t], acc);
  }
}

// ---------------- P2: z = T0'*Yt'^T/N + coef*w2sp + s2*coef + ow_b ----------
__global__ __launch_bounds__(256) void p2_k(char* __restrict__ ws,
                                            const float* __restrict__ ow_b)
{
  const int blk = blockIdx.x, t = threadIdx.x;
  __shared__ __attribute__((aligned(16))) __bf16 Al[2][64][72];
  __shared__ __attribute__((aligned(16))) __bf16 Bl[2][64][72];
  float* shf = (float*)(&Al[0][0][0]);

  const int lane = t & 63, wv = t >> 6;
  const int wm = (wv & 1) * 32, wn = (wv >> 1) * 32;
  const int fr = lane & 15, rbase = (lane >> 4) * 4;

  const int b = blk >> 6, t6 = blk & 63;
  const int mt = t6 >> 4, nt = t6 & 15;
  const int m0 = mt * 64, n0 = nt * 64;
  (void)nt;

  f32x4 acc[2][2]; ZERO_ACC(acc);
  gemm_acc((const __bf16*)(ws + OFF_T0) + (size_t)b * 65536,
           (const __bf16*)(ws + OFF_YT) + (size_t)b * 262144,
           256, m0, n0, Al, Bl, acc);

  const float* uv   = (const float*)(ws + OFF_UV);
  const float* cvec = (const float*)(ws + OFF_CVEC);
  const float* w2sp = (const float*)(ws + OFF_W2SP);
  const float s2v   = *(const float*)(ws + OFF_S2);
  float* SRAW = (float*)(ws + OFF_STATS);
  float* zb = (float*)(ws + OFF_Z) + (size_t)b * 262144;

  float gs[2] = {0.f, 0.f}, gq[2] = {0.f, 0.f};
  int gidx[2];
  const float s1024 = 1.f / 1024.f;
#pragma unroll
  for (int i = 0; i < 2; ++i) {
    gidx[i] = (wm + i * 16 + rbase) >> 3;
#pragma unroll
    for (int r = 0; r < 4; ++r) {
      int m = m0 + wm + i * 16 + rbase + r;
      float coefm = uv[m] + cvec[b * 256 + m] * s1024;
      float qm = s2v * coefm + ow_b[m];
#pragma unroll
      for (int j = 0; j < 2; ++j) {
        int n = n0 + wn + j * 16 + fr;
        float w2n = w2sp[b * 1024 + n] + w2sp[4096 + b * 1024 + n];
        float v = acc[i][j][r] * s1024 + coefm * w2n + qm;
        zb[(size_t)m * 1024 + n] = v;
        gs[i] += v;
        gq[i] += v * v;
      }
    }
  }
  __syncthreads();
  if (t < 16) shf[t] = 0.f;
  __syncthreads();
#pragma unroll
  for (int i = 0; i < 2; ++i) {
    atomicAdd(&shf[gidx[i] * 2], gs[i]);
    atomicAdd(&shf[gidx[i] * 2 + 1], gq[i]);
  }
  __syncthreads();
  if (t < 16) {
    int g = mt * 8 + (t >> 1);
    atomicAdd(&SRAW[(b * 32 + g) * 2 + (t & 1)], shf[t]);
  }
}

// ---------------- fused GN + residual scatter (float4) ----------------------
__device__ __forceinline__ float4 gmix(float4 bz, float4 zz, float a, float c)
{
  float4 r;
  r.x = bz.x + zz.x * a + c;
  r.y = bz.y + zz.y * a + c;
  r.z = bz.z + zz.z * a + c;
  r.w = bz.w + zz.w * a + c;
  return r;
}
__device__ __forceinline__ float max4(float4 v)
{ return fmaxf(fmaxf(v.x, v.y), fmaxf(v.z, v.w)); }

// raw (sum, sumsq) -> (a = inv*gamma, c0 = beta - mean*a)
__device__ __forceinline__ void gn_coeff(const float2* __restrict__ ST,
                                         const float* __restrict__ gamma,
                                         const float* __restrict__ beta,
                                         int b, int ch, float& a, float& c0)
{
  float2 sq = ST[b * 32 + (ch >> 3)];
  float mean = sq.x * (1.0f / 8192.0f);
  float var  = sq.y * (1.0f / 8192.0f) - mean * mean;
  float inv  = rsqrtf(var + 1e-5f);
  a  = inv * gamma[ch];
  c0 = beta[ch] - mean * a;
}

__global__ __launch_bounds__(256) void scat_k(
    const char* __restrict__ ws,
    const float* __restrict__ f0, const float* __restrict__ f1,
    const float* __restrict__ f2, const float* __restrict__ f3,
    const float* __restrict__ f4,
    const float* __restrict__ gamma, const float* __restrict__ beta,
    float* __restrict__ out)
{
  const float* Z = (const float*)(ws + OFF_Z);
  const float* BSF = (const float*)(ws + OFF_BSF);
  const float2* ST = (const float2*)(ws + OFF_STATS);
  const int i4 = blockIdx.x * 256 + threadIdx.x;

  if (i4 < 4194304) {                       // f0: 128x128, upsample x4
    const int l = i4 << 2;
    const int x = l & 127, yy = (l >> 7) & 127, nc = l >> 14;
    const int ch = nc & 255, b = nc >> 8;
    float a, c0; gn_coeff(ST, gamma, beta, b, ch, a, c0);
    size_t base = (size_t)nc * 1024 + ((yy >> 2) << 5) + (x >> 2);
    float v = BSF[base] + Z[base] * a + c0;
    float4 f = ((const float4*)f0)[i4];
    float4 o; o.x = f.x + v; o.y = f.y + v; o.z = f.z + v; o.w = f.w + v;
    ((float4*)out)[i4] = o;
  } else if (i4 < 5242880) {                // f1: 64x64, upsample x2
    const int l4 = i4 - 4194304;
    const int l = l4 << 2;
    const int x = l & 63, yy = (l >> 6) & 63, nc = l >> 12;
    const int ch = nc & 255, b = nc >> 8;
    float a, c0; gn_coeff(ST, gamma, beta, b, ch, a, c0);
    size_t base = (size_t)nc * 1024 + ((yy >> 1) << 5) + (x >> 1);
    float v0 = BSF[base] + Z[base] * a + c0;
    float v1 = BSF[base + 1] + Z[base + 1] * a + c0;
    float4 f = ((const float4*)f1)[l4];
    float4 o; o.x = f.x + v0; o.y = f.y + v0; o.z = f.z + v1; o.w = f.w + v1;
    ((float4*)out)[i4] = o;
  } else if (i4 < 5505024) {                // f2: 32x32, identity
    const int l4 = i4 - 5242880;
    const int l = l4 << 2;
    const int nc = l >> 10, e = l & 1023;
    const int ch = nc & 255, b = nc >> 8;
    float a, c0; gn_coeff(ST, gamma, beta, b, ch, a, c0);
    size_t base = (size_t)nc * 1024 + e;
    float4 z4 = *(const float4*)&Z[base];
    float4 b4 = *(const float4*)&BSF[base];
    float4 v = gmix(b4, z4, a, c0);
    float4 f = ((const float4*)f2)[l4];
    float4 o; o.x = f.x + v.x; o.y = f.y + v.y; o.z = f.z + v.z; o.w = f.w + v.w;
    ((float4*)out)[i4] = o;
  } else if (i4 < 5570560) {                // f3: 16x16, maxpool 2x2
    const int l4 = i4 - 5505024;
    const int l = l4 << 2;
    const int x = l & 15, yy = (l >> 4) & 15, nc = l >> 8;
    const int ch = nc & 255, b = nc >> 8;
    float a, c0; gn_coeff(ST, gamma, beta, b, ch, a, c0);
    size_t base = (size_t)nc * 1024;
    const int p0 = (yy * 2) * 32 + (x * 2);
    float4 r0a = gmix(*(const float4*)&BSF[base + p0],      *(const float4*)&Z[base + p0],      a, c0);
    float4 r0b = gmix(*(const float4*)&BSF[base + p0 + 4],  *(const float4*)&Z[base + p0 + 4],  a, c0);
    float4 r1a = gmix(*(const float4*)&BSF[base + p0 + 32], *(const float4*)&Z[base + p0 + 32], a, c0);
    float4 r1b = gmix(*(const float4*)&BSF[base + p0 + 36], *(const float4*)&Z[base + p0 + 36], a, c0);
    float4 f = ((const float4*)f3)[l4];
    float4 o;
    o.x = f.x + fmaxf(fmaxf(r0a.x, r0a.y), fmaxf(r1a.x, r1a.y));
    o.y = f.y + fmaxf(fmaxf(r0a.z, r0a.w), fmaxf(r1a.z, r1a.w));
    o.z = f.z + fmaxf(fmaxf(r0b.x, r0b.y), fmaxf(r1b.x, r1b.y));
    o.w = f.w + fmaxf(fmaxf(r0b.z, r0b.w), fmaxf(r1b.z, r1b.w));
    ((float4*)out)[i4] = o;
  } else {                                   // f4: 8x8, maxpool 4x4
    const int l4 = i4 - 5570560;
    const int l = l4 << 2;
    const int x = l & 7, yy = (l >> 3) & 7, nc = l >> 6;
    const int ch = nc & 255, b = nc >> 8;
    float a, c0; gn_coeff(ST, gamma, beta, b, ch, a, c0);
    size_t base = (size_t)nc * 1024;
    float4 mx = {-3.4e38f, -3.4e38f, -3.4e38f, -3.4e38f};
#pragma unroll
    for (int r = 0; r < 4; ++r) {
      const float* zp = &Z[base + (size_t)(yy * 4 + r) * 32 + x * 4];
      const float* bp = &BSF[base + (size_t)(yy * 4 + r) * 32 + x * 4];
      float4 q0 = gmix(*(const float4*)(bp),      *(const float4*)(zp),      a, c0);
      float4 q1 = gmix(*(const float4*)(bp + 4),  *(const float4*)(zp + 4),  a, c0);
      float4 q2 = gmix(*(const float4*)(bp + 8),  *(const float4*)(zp + 8),  a, c0);
      float4 q3 = gmix(*(const float4*)(bp + 12), *(const float4*)(zp + 12), a, c0);
      mx.x = fmaxf(mx.x, max4(q0));
      mx.y = fmaxf(mx.y, max4(q1));
      mx.z = fmaxf(mx.z, max4(q2));
      mx.w = fmaxf(mx.w, max4(q3));
    }
    float4 f = ((const float4*)f4)[l4];
    float4 o; o.x = f.x + mx.x; o.y = f.y + mx.y; o.z = f.z + mx.z; o.w = f.w + mx.w;
    ((float4*)out)[i4] = o;
  }
}

// ---------------------------------------------------------------------------
extern "C" void kernel_launch(void* const* d_in, const int* in_sizes, int n_in,
                              void* d_out, int out_size, void* d_ws, size_t ws_size,
                              hipStream_t stream)
{
  (void)in_sizes; (void)n_in; (void)out_size; (void)ws_size;
  const float* f0   = (const float*)d_in[0];
  const float* f1   = (const float*)d_in[1];
  const float* f2   = (const float*)d_in[2];
  const float* f3   = (const float*)d_in[3];
  const float* f4   = (const float*)d_in[4];
  const float* g_w  = (const float*)d_in[5];
  const float* g_b  = (const float*)d_in[6];
  const float* th_w = (const float*)d_in[7];
  const float* th_b = (const float*)d_in[8];
  const float* ph_w = (const float*)d_in[9];
  const float* ph_b = (const float*)d_in[10];
  const float* ow_w = (const float*)d_in[11];
  const float* ow_b = (const float*)d_in[12];
  const float* gn_g = (const float*)d_in[13];
  const float* gn_b = (const float*)d_in[14];
  char* ws = (char*)d_ws;

  // 1) gather + weight prep (all matvecs chunk-parallel)
  prep_k<<<334, 256, 0, stream>>>(f0, f1, f2, f3, f4,
                                  g_w, ph_w, th_w, ow_w,
                                  g_b, ph_b, th_b, ws);
  // 2) S (hi/lo) ; U+UT ; V ; r ; w2sp parts
  p0_k<<<129, 256, 0, stream>>>(ws);
  // 3) T0' ; Yt(+v2 fold) ; cvec
  p1_k<<<336, 256, 0, stream>>>(ws);
  // 4) z + GN raw stats
  p2_k<<<256, 256, 0, stream>>>(ws, ow_b);
  // 5) fused GN-normalize + residual scatter
  scat_k<<<21824, 256, 0, stream>>>(ws, f0, f1, f2, f3, f4, gn_g, gn_b,
                                    (float*)d_out);
}